// Round 4
// baseline (616.102 us; speedup 1.0000x reference)
//
#include <hip/hip_runtime.h>
#include <hip/hip_bf16.h>

// Problem: B=8, S=1024, H=1024, NH=16, DH=64.
// Inputs fp32 (confirmed: round-1 NaN from fp32-read-as-bf16; sniffer kept for
// robustness). OUTPUT WRITTEN AS FLOAT32 this round (reference returns f32;
// round-2/3 absmax 0.1047 matches bf16-written-to-f32-buffer decimation).
// Mask dtype sniffed 4-way (i32/i8/f32/bf16) -> flags[1].
// d_ws footprint kept to 32MB+64B (H2 hardening): no convert pass; GEMM
// stages fp32->bf16 on the fly. Qb+Kb live in d_out (32MB f32).
#define Bn 8
#define Sn 1024
#define Hn 1024
#define NHn 16
#define DHn 64
#define Mn (Bn * Sn) // 8192 rows for all projections

typedef unsigned short u16;
typedef short bf16x8 __attribute__((ext_vector_type(8)));
typedef float f32x4 __attribute__((ext_vector_type(4)));

__device__ __forceinline__ u16 f2bf(float x) {
  union { __hip_bfloat16 h; u16 u; } cv;
  cv.h = __float2bfloat16(x);
  return cv.u;
}

__device__ __forceinline__ float bf2f(u16 x) {
  union { u16 u; __hip_bfloat16 h; } cv;
  cv.u = x;
  return __bfloat162float(cv.h);
}

// Load 8 consecutive elements starting at element index idx as bf16x8,
// converting from f32 when isF32 (uniform flag).
__device__ __forceinline__ bf16x8 ld8(const void* p, size_t idx, int isF32) {
  if (isF32) {
    const float* f = (const float*)p + idx;
    f32x4 lo = *(const f32x4*)f;
    f32x4 hi = *(const f32x4*)(f + 4);
    bf16x8 o;
#pragma unroll
    for (int j = 0; j < 4; ++j) {
      o[j]     = (short)f2bf(lo[j]);
      o[4 + j] = (short)f2bf(hi[j]);
    }
    return o;
  }
  return *(const bf16x8*)((const u16*)p + idx);
}

// ---------------------------------------------------------------------------
// Dtype sniffer. flags[0]=1 if float tensors are fp32 (else bf16).
// flags[1] = mask dtype: 0=int32, 1=int8/bool, 2=bf16, 3=f32.
// Deterministic, recomputed every call (graph-capture safe).
// ---------------------------------------------------------------------------
__global__ __launch_bounds__(256) void sniff_k(const void* __restrict__ w,
                                               const void* __restrict__ mask,
                                               int* __restrict__ flags) {
  __shared__ int cF, viol;
  if (threadIdx.x == 0) { cF = 0; viol = 0; }
  __syncthreads();
  {
    u16 u = ((const u16*)w)[threadIdx.x];
    if (((u >> 7) & 0xFF) >= 128) atomicAdd(&cF, 1); // impossible for bf16 N(0,0.02^2)
  }
  {
    const unsigned* mw = (const unsigned*)mask;
    int vb = 0;
#pragma unroll
    for (int j = 0; j < 8; ++j) {
      unsigned v = mw[threadIdx.x * 8 + j];          // first 8192B: in-bounds for all dtypes
      if (v > 1u) vb |= 1;                           // not i32 0/1
      if ((v & 0xFEFEFEFEu) != 0u) vb |= 2;          // not i8 0/1
      if (!(v == 0u || v == 0x3F800000u)) vb |= 4;   // not f32 0/1
      unsigned h0 = v & 0xFFFFu, h1 = v >> 16;
      if (!((h0 == 0u || h0 == 0x3F80u) &&
            (h1 == 0u || h1 == 0x3F80u))) vb |= 8;   // not bf16 0/1
    }
    if (vb) atomicOr(&viol, vb);
  }
  __syncthreads();
  if (threadIdx.x == 0) {
    flags[0] = (cF > 4) ? 1 : 0;
    int mt;
    if (!(viol & 1))      mt = 0;
    else if (!(viol & 2)) mt = 1;
    else if (!(viol & 4)) mt = 3;   // f32 before bf16 (f32 patterns pass bf16 test)
    else if (!(viol & 8)) mt = 2;
    else                  mt = 0;
    flags[1] = mt;
  }
}

// ---------------------------------------------------------------------------
// O[M,N] = (X[M,K] @ W[N,K]^T + bias[N]) * scale, fp32 accum.
// A/B/bias dtype: bf16, or fp32 when (side-mode && flags[0]).
// Output: f32 when oF32 else bf16. 128x128 tile, BK=32, 4 waves of 64x64.
// ---------------------------------------------------------------------------
__global__ __launch_bounds__(256) void gemm_flex(
    const void* __restrict__ X, const void* __restrict__ W,
    const void* __restrict__ bias, void* __restrict__ O,
    int M, int N, int K, float scale,
    int aFlex, int bFlex, int oF32, const int* __restrict__ flags)
{
  __shared__ __attribute__((aligned(16))) u16 As[128 * 32];
  __shared__ __attribute__((aligned(16))) u16 Bs[128 * 32];
  const int aF32 = aFlex ? flags[0] : 0;
  const int bF32 = bFlex ? flags[0] : 0;
  const int tid  = threadIdx.x;
  const int wave = tid >> 6;
  const int lane = tid & 63;
  const int ln   = lane & 15;
  const int quad = lane >> 4;
  const int m0 = blockIdx.x * 128;
  const int n0 = blockIdx.y * 128;
  const int wm = (wave & 1) * 64;
  const int wn = (wave >> 1) * 64;

  const int sr = tid >> 2;        // staging row 0..63 (and +64)
  const int sc = (tid & 3) * 8;   // 8-elem column chunk

  f32x4 acc[4][4] = {};

  for (int k0 = 0; k0 < K; k0 += 32) {
    bf16x8 a0 = ld8(X, (size_t)(m0 + sr) * K + k0 + sc, aF32);
    bf16x8 a1 = ld8(X, (size_t)(m0 + 64 + sr) * K + k0 + sc, aF32);
    bf16x8 b0 = ld8(W, (size_t)(n0 + sr) * K + k0 + sc, bF32);
    bf16x8 b1 = ld8(W, (size_t)(n0 + 64 + sr) * K + k0 + sc, bF32);
    *(bf16x8*)&As[sr * 32 + sc]        = a0;
    *(bf16x8*)&As[(64 + sr) * 32 + sc] = a1;
    *(bf16x8*)&Bs[sr * 32 + sc]        = b0;
    *(bf16x8*)&Bs[(64 + sr) * 32 + sc] = b1;
    __syncthreads();
    bf16x8 af[4], bfr[4];
#pragma unroll
    for (int t = 0; t < 4; ++t)
      af[t] = *(const bf16x8*)&As[(wm + t * 16 + ln) * 32 + quad * 8];
#pragma unroll
    for (int t = 0; t < 4; ++t)
      bfr[t] = *(const bf16x8*)&Bs[(wn + t * 16 + ln) * 32 + quad * 8];
#pragma unroll
    for (int i = 0; i < 4; ++i)
#pragma unroll
      for (int j = 0; j < 4; ++j)
        acc[i][j] = __builtin_amdgcn_mfma_f32_16x16x32_bf16(af[i], bfr[j], acc[i][j], 0, 0, 0);
    __syncthreads();
  }

  // C/D layout: col = lane&15 (+16*j), row = quad*4 + r (m89-verified)
#pragma unroll
  for (int j = 0; j < 4; ++j) {
    const int col = n0 + wn + j * 16 + ln;
    const float bv = bF32 ? ((const float*)bias)[col] : bf2f(((const u16*)bias)[col]);
#pragma unroll
    for (int i = 0; i < 4; ++i) {
      const int rowb = m0 + wm + i * 16 + quad * 4;
#pragma unroll
      for (int r = 0; r < 4; ++r) {
        const float val = (acc[i][j][r] + bv) * scale;
        const size_t idx = (size_t)(rowb + r) * N + col;
        if (oF32) ((float*)O)[idx] = val;
        else      ((u16*)O)[idx]   = f2bf(val);
      }
    }
  }
}

// ---------------------------------------------------------------------------
// Flash attention: one block per (b, h, 64-row Q tile). 4 waves x 16 Q-rows.
// Qb pre-scaled by 1/8. Qb/Kb/Vb bf16 row-major [B*S, H]. Ctx bf16 [B*S, H].
// ---------------------------------------------------------------------------
__global__ __launch_bounds__(256) void attn(
    const u16* __restrict__ Qb, const u16* __restrict__ Kb,
    const u16* __restrict__ Vb, const void* __restrict__ mask,
    const int* __restrict__ flags, u16* __restrict__ Ctx)
{
  __shared__ __attribute__((aligned(16))) float maskf[Sn];
  __shared__ __attribute__((aligned(16))) u16 Vt[64 * 72];    // V^T [d][kv], pad 64->72
  __shared__ __attribute__((aligned(16))) u16 Pl[4][16 * 72]; // per-wave P strip

  const int tid  = threadIdx.x;
  const int wave = tid >> 6;
  const int lane = tid & 63;
  const int ln   = lane & 15;
  const int quad = lane >> 4;
  const int qt = blockIdx.x & 15;
  const int bh = blockIdx.x >> 4;
  const int b  = bh >> 4;
  const int h  = bh & 15;

  const int mt = flags[1];
  for (int i = tid; i < Sn; i += 256) {
    const int idx = b * Sn + i;
    int nz;
    if (mt == 0)      nz = ((const int*)mask)[idx] != 0;
    else if (mt == 1) nz = ((const signed char*)mask)[idx] != 0;
    else if (mt == 2) nz = ((const u16*)mask)[idx] != 0;
    else              nz = ((const unsigned*)mask)[idx] != 0;
    maskf[i] = nz ? -1e9f : 0.0f;
  }

  // Q fragments (A-operand: m=lane&15, k=quad*8+j)
  const int srow = b * Sn + qt * 64 + wave * 16 + ln;
  const size_t qoff = (size_t)srow * Hn + h * DHn;
  bf16x8 qf0 = *(const bf16x8*)&Qb[qoff + quad * 8];
  bf16x8 qf1 = *(const bf16x8*)&Qb[qoff + 32 + quad * 8];

  float mrun[4], lrun[4];
#pragma unroll
  for (int r = 0; r < 4; ++r) { mrun[r] = -INFINITY; lrun[r] = 0.0f; }
  f32x4 acc[4] = {};

  const int vkv = tid & 63;
  const int vdc = tid >> 6;
  u16* pw = Pl[wave];

  for (int t16 = 0; t16 < 16; ++t16) {
    const int kv0 = t16 * 64;
    __syncthreads(); // previous Vt/Pl fully consumed
#pragma unroll
    for (int cc = 0; cc < 2; ++cc) {
      const int dc = vdc + cc * 4;
      bf16x8 vv = *(const bf16x8*)&Vb[(size_t)(b * Sn + kv0 + vkv) * Hn + h * DHn + dc * 8];
#pragma unroll
      for (int j = 0; j < 8; ++j)
        Vt[(dc * 8 + j) * 72 + vkv] = (u16)vv[j];
    }
    __syncthreads();

    // S = Q K^T. B-operand: n=lane&15 -> K row, k=quad*8+j contiguous.
    f32x4 sc[4];
#pragma unroll
    for (int t = 0; t < 4; ++t) {
      const size_t krow = (size_t)(b * Sn + kv0 + t * 16 + ln) * Hn + h * DHn;
      bf16x8 kf0 = *(const bf16x8*)&Kb[krow + quad * 8];
      bf16x8 kf1 = *(const bf16x8*)&Kb[krow + 32 + quad * 8];
      f32x4 z = {};
      z = __builtin_amdgcn_mfma_f32_16x16x32_bf16(qf0, kf0, z, 0, 0, 0);
      z = __builtin_amdgcn_mfma_f32_16x16x32_bf16(qf1, kf1, z, 0, 0, 0);
      sc[t] = z;
    }
    float mf[4];
#pragma unroll
    for (int t = 0; t < 4; ++t) mf[t] = maskf[kv0 + t * 16 + ln];
#pragma unroll
    for (int t = 0; t < 4; ++t)
#pragma unroll
      for (int r = 0; r < 4; ++r) sc[t][r] += mf[t];

    // online softmax; row m = quad*4+r lives in the 16 lanes of this quad
    float al[4], mx[4];
#pragma unroll
    for (int r = 0; r < 4; ++r) {
      float v = fmaxf(fmaxf(sc[0][r], sc[1][r]), fmaxf(sc[2][r], sc[3][r]));
      v = fmaxf(v, __shfl_xor(v, 1));
      v = fmaxf(v, __shfl_xor(v, 2));
      v = fmaxf(v, __shfl_xor(v, 4));
      v = fmaxf(v, __shfl_xor(v, 8));
      const float mnew = fmaxf(mrun[r], v);
      al[r] = __expf(mrun[r] - mnew);
      mrun[r] = mnew;
      mx[r] = mnew;
    }
#pragma unroll
    for (int r = 0; r < 4; ++r) {
      float s = 0.0f;
#pragma unroll
      for (int t = 0; t < 4; ++t) {
        const float p = __expf(sc[t][r] - mx[r]);
        sc[t][r] = p;
        s += p;
      }
      s += __shfl_xor(s, 1);
      s += __shfl_xor(s, 2);
      s += __shfl_xor(s, 4);
      s += __shfl_xor(s, 8);
      lrun[r] = lrun[r] * al[r] + s;
    }
    // P: C-layout -> per-wave LDS -> A-layout (barrier for write->read ordering)
#pragma unroll
    for (int t = 0; t < 4; ++t)
#pragma unroll
      for (int r = 0; r < 4; ++r)
        pw[(quad * 4 + r) * 72 + t * 16 + ln] = f2bf(sc[t][r]);
    __syncthreads();
#pragma unroll
    for (int dt = 0; dt < 4; ++dt)
#pragma unroll
      for (int r = 0; r < 4; ++r) acc[dt][r] *= al[r];
    bf16x8 pa0 = *(const bf16x8*)&pw[ln * 72 + quad * 8];
    bf16x8 pa1 = *(const bf16x8*)&pw[ln * 72 + 32 + quad * 8];
#pragma unroll
    for (int dt = 0; dt < 4; ++dt) {
      bf16x8 vb0 = *(const bf16x8*)&Vt[(dt * 16 + ln) * 72 + quad * 8];
      bf16x8 vb1 = *(const bf16x8*)&Vt[(dt * 16 + ln) * 72 + 32 + quad * 8];
      acc[dt] = __builtin_amdgcn_mfma_f32_16x16x32_bf16(pa0, vb0, acc[dt], 0, 0, 0);
      acc[dt] = __builtin_amdgcn_mfma_f32_16x16x32_bf16(pa1, vb1, acc[dt], 0, 0, 0);
    }
  }

#pragma unroll
  for (int dt = 0; dt < 4; ++dt)
#pragma unroll
    for (int r = 0; r < 4; ++r) {
      const int s = qt * 64 + wave * 16 + quad * 4 + r;
      Ctx[(size_t)(b * Sn + s) * Hn + h * DHn + dt * 16 + ln] = f2bf(acc[dt][r] / lrun[r]);
    }
}

extern "C" void kernel_launch(void* const* d_in, const int* in_sizes, int n_in,
                              void* d_out, int out_size, void* d_ws, size_t ws_size,
                              hipStream_t stream) {
  const void* v    = d_in[0];
  const void* k    = d_in[1];
  const void* q    = d_in[2];
  const void* mask = d_in[3];
  const void* Wq   = d_in[4];
  const void* bq   = d_in[5];
  const void* Wk   = d_in[6];
  const void* bk   = d_in[7];
  const void* Wv   = d_in[8];
  const void* bv   = d_in[9];
  const void* Wm   = d_in[10];
  const void* bm   = d_in[11];

  // d_ws footprint: 64B flags + 16MB Vb + 16MB Cx = 32MB + 64B.
  int* flags = (int*)d_ws;
  u16* Vb = (u16*)((char*)d_ws + 64);
  u16* Cx = Vb + (size_t)Mn * Hn;
  // Qb+Kb live in d_out (32MB f32 output buffer holds 2x16MB bf16 scratch
  // until the final GEMM overwrites it; both consumed by attn before that).
  u16* Qb = (u16*)d_out;
  u16* Kb = Qb + (size_t)Mn * Hn;

  sniff_k<<<1, 256, 0, stream>>>(Wq, mask, flags);

  dim3 grid(Mn / 128, Hn / 128), blk(256);
  gemm_flex<<<grid, blk, 0, stream>>>(q, Wq, bq, Qb, Mn, Hn, Hn, 0.125f, 1, 1, 0, flags);
  gemm_flex<<<grid, blk, 0, stream>>>(k, Wk, bk, Kb, Mn, Hn, Hn, 1.0f, 1, 1, 0, flags);
  gemm_flex<<<grid, blk, 0, stream>>>(v, Wv, bv, Vb, Mn, Hn, Hn, 1.0f, 1, 1, 0, flags);
  attn<<<dim3(Bn * NHn * (Sn / 64)), blk, 0, stream>>>(Qb, Kb, Vb, mask, flags, Cx);
  gemm_flex<<<grid, blk, 0, stream>>>(Cx, Wm, bm, d_out, Mn, Hn, Hn, 1.0f, 0, 1, 1, flags);
}

// Round 5
// 390.728 us; speedup vs baseline: 1.5768x; 1.5768x over previous
//
#include <hip/hip_runtime.h>
#include <hip/hip_bf16.h>

// B=8, S=1024, H=1024, NH=16, DH=64. Inputs fp32 (proven r1/r4), output f32
// (proven r4), mask dtype sniffed 4-way. All GEMMs pure bf16 after a convert
// pass; V projection writes per-head-TRANSPOSED Vbt so attention stages V
// coalesced with no scatter. K staged through LDS (kills 4x/wave L2 re-reads).
#define Bn 8
#define Sn 1024
#define Hn 1024
#define NHn 16
#define DHn 64
#define Mn (Bn * Sn)

typedef unsigned short u16;
typedef short bf16x8 __attribute__((ext_vector_type(8)));
typedef unsigned short u16x4 __attribute__((ext_vector_type(4)));
typedef float f32x4 __attribute__((ext_vector_type(4)));

__device__ __forceinline__ u16 f2bf(float x) {
  union { __hip_bfloat16 h; u16 u; } cv;
  cv.h = __float2bfloat16(x);
  return cv.u;
}

__device__ __forceinline__ void async_ld16(void* lds, const void* g) {
  __builtin_amdgcn_global_load_lds(
      (const __attribute__((address_space(1))) void*)g,
      (__attribute__((address_space(3))) void*)lds, 16, 0, 0);
}

// ---------------------------------------------------------------------------
// Mask dtype sniffer: flags[1] = 0:i32 1:i8 2:bf16 3:f32 (f32 before bf16).
// Deterministic every call (graph-safe).
// ---------------------------------------------------------------------------
__global__ __launch_bounds__(256) void sniff_k(const void* __restrict__ mask,
                                               int* __restrict__ flags) {
  __shared__ int viol;
  if (threadIdx.x == 0) viol = 0;
  __syncthreads();
  const unsigned* mw = (const unsigned*)mask;
  int vb = 0;
#pragma unroll
  for (int j = 0; j < 8; ++j) {
    unsigned v = mw[threadIdx.x * 8 + j];          // first 8192B valid for all dtypes
    if (v > 1u) vb |= 1;
    if ((v & 0xFEFEFEFEu) != 0u) vb |= 2;
    if (!(v == 0u || v == 0x3F800000u)) vb |= 4;
    unsigned h0 = v & 0xFFFFu, h1 = v >> 16;
    if (!((h0 == 0u || h0 == 0x3F80u) && (h1 == 0u || h1 == 0x3F80u))) vb |= 8;
  }
  if (vb) atomicOr(&viol, vb);
  __syncthreads();
  if (threadIdx.x == 0) {
    int mt;
    if (!(viol & 1))      mt = 0;
    else if (!(viol & 2)) mt = 1;
    else if (!(viol & 4)) mt = 3;
    else if (!(viol & 8)) mt = 2;
    else                  mt = 0;
    flags[1] = mt;
  }
}

// fp32 -> bf16: three equal tensors of 8388608 elems, one thread = 8 elems.
__global__ __launch_bounds__(256) void convert3(
    const float* __restrict__ a, const float* __restrict__ b,
    const float* __restrict__ c, u16* __restrict__ da,
    u16* __restrict__ db, u16* __restrict__ dc) {
  const int seg = blockIdx.x >> 12;                 // 4096 blocks per tensor
  const int bid = blockIdx.x & 4095;
  const float* s = seg == 0 ? a : seg == 1 ? b : c;
  u16* d        = seg == 0 ? da : seg == 1 ? db : dc;
  const int i = (bid * 256 + threadIdx.x) * 8;
  f32x4 lo = *(const f32x4*)(s + i);
  f32x4 hi = *(const f32x4*)(s + i + 4);
  bf16x8 o;
#pragma unroll
  for (int j = 0; j < 4; ++j) { o[j] = (short)f2bf(lo[j]); o[4 + j] = (short)f2bf(hi[j]); }
  *(bf16x8*)(d + i) = o;
}

// fp32 -> bf16: four 1048576-elem weights.
__global__ __launch_bounds__(256) void convertW(
    const float* __restrict__ a, const float* __restrict__ b,
    const float* __restrict__ c, const float* __restrict__ e,
    u16* __restrict__ da, u16* __restrict__ db,
    u16* __restrict__ dc, u16* __restrict__ de) {
  const int seg = blockIdx.x >> 9;                  // 512 blocks per tensor
  const int bid = blockIdx.x & 511;
  const float* s = seg == 0 ? a : seg == 1 ? b : seg == 2 ? c : e;
  u16* d        = seg == 0 ? da : seg == 1 ? db : seg == 2 ? dc : de;
  const int i = (bid * 256 + threadIdx.x) * 8;
  f32x4 lo = *(const f32x4*)(s + i);
  f32x4 hi = *(const f32x4*)(s + i + 4);
  bf16x8 o;
#pragma unroll
  for (int j = 0; j < 4; ++j) { o[j] = (short)f2bf(lo[j]); o[4 + j] = (short)f2bf(hi[j]); }
  *(bf16x8*)(d + i) = o;
}

// ---------------------------------------------------------------------------
// O = (X[8192,1024] @ W[1024,1024]^T + bias)*scale, bf16 in, fp32 accum.
// 128x128 tile, BK=32, global_load_lds width=16 (m97 structure).
// OMODE 0: bf16 row-major. 1: f32 row-major. 2: bf16 per-head transposed
// Vbt[(b*1024+col)*1024 + s] with packed b64 stores (V projection).
// ---------------------------------------------------------------------------
template <int OMODE>
__global__ __launch_bounds__(256) void gemm_bt(
    const u16* __restrict__ X, const u16* __restrict__ W,
    const float* __restrict__ bias, void* __restrict__ O, float scale)
{
  __shared__ __attribute__((aligned(16))) u16 As[128 * 32];
  __shared__ __attribute__((aligned(16))) u16 Bs[128 * 32];
  const int tid  = threadIdx.x;
  const int wave = tid >> 6;
  const int lane = tid & 63;
  const int ln   = lane & 15;
  const int quad = lane >> 4;
  const int m0 = blockIdx.x * 128;
  const int n0 = blockIdx.y * 128;
  const int wm = (wave & 1) * 64;
  const int wn = (wave >> 1) * 64;
  const int r0 = tid >> 2;          // staging row 0..63 (and +64)
  const int oc = (tid & 3) * 8;     // 16B column chunk
  char* A0 = (char*)As + wave * 1024;        // dest = base + lane*16 (HW rule)
  char* A1 = (char*)As + 4096 + wave * 1024;
  char* B0 = (char*)Bs + wave * 1024;
  char* B1 = (char*)Bs + 4096 + wave * 1024;

  f32x4 acc[4][4] = {};

  for (int k0 = 0; k0 < 1024; k0 += 32) {
    async_ld16(A0, X + (size_t)(m0 + r0) * 1024 + k0 + oc);
    async_ld16(A1, X + (size_t)(m0 + 64 + r0) * 1024 + k0 + oc);
    async_ld16(B0, W + (size_t)(n0 + r0) * 1024 + k0 + oc);
    async_ld16(B1, W + (size_t)(n0 + 64 + r0) * 1024 + k0 + oc);
    __syncthreads();
    bf16x8 af[4], bf[4];
#pragma unroll
    for (int t = 0; t < 4; ++t)
      af[t] = *(const bf16x8*)&As[(wm + t * 16 + ln) * 32 + quad * 8];
#pragma unroll
    for (int t = 0; t < 4; ++t)
      bf[t] = *(const bf16x8*)&Bs[(wn + t * 16 + ln) * 32 + quad * 8];
#pragma unroll
    for (int i = 0; i < 4; ++i)
#pragma unroll
      for (int j = 0; j < 4; ++j)
        acc[i][j] = __builtin_amdgcn_mfma_f32_16x16x32_bf16(af[i], bf[j], acc[i][j], 0, 0, 0);
    __syncthreads();
  }

  // C/D: col = lane&15 (+16j), row = quad*4 + r
  if (OMODE == 2) {
    const int bb = m0 >> 10;          // batch (tile never crosses batches)
    const int sb = m0 & 1023;
#pragma unroll
    for (int j = 0; j < 4; ++j) {
      const int col = n0 + wn + j * 16 + ln;
      const float bv = bias[col];
#pragma unroll
      for (int i = 0; i < 4; ++i) {
        const int sl = sb + wm + i * 16 + quad * 4;
        u16x4 pk;
#pragma unroll
        for (int r = 0; r < 4; ++r) pk[r] = f2bf((acc[i][j][r] + bv) * scale);
        *(u16x4*)&((u16*)O)[((size_t)(bb * 1024 + col)) * 1024 + sl] = pk;
      }
    }
  } else {
#pragma unroll
    for (int j = 0; j < 4; ++j) {
      const int col = n0 + wn + j * 16 + ln;
      const float bv = bias[col];
#pragma unroll
      for (int i = 0; i < 4; ++i) {
        const int rowb = m0 + wm + i * 16 + quad * 4;
#pragma unroll
        for (int r = 0; r < 4; ++r) {
          const float val = (acc[i][j][r] + bv) * scale;
          const size_t idx = (size_t)(rowb + r) * 1024 + col;
          if (OMODE == 1) ((float*)O)[idx] = val;
          else            ((u16*)O)[idx]   = f2bf(val);
        }
      }
    }
  }
}

// ---------------------------------------------------------------------------
// Flash attention v2: block = (b,h,64-row Q tile), 4 waves x 16 Q-rows,
// KV-tile 128 (8 iterations). K staged via LDS (once per block). V read from
// pre-transposed Vbt [B*NH*DH, S] -> coalesced stage, no scatter.
// ---------------------------------------------------------------------------
__global__ __launch_bounds__(256) void attn(
    const u16* __restrict__ Qb, const u16* __restrict__ Kb,
    const u16* __restrict__ Vbt, const void* __restrict__ mask,
    const int* __restrict__ flags, u16* __restrict__ Ctx)
{
  __shared__ __attribute__((aligned(16))) u16 Ks[128 * 72];    // [kv][d] pad 64->72
  __shared__ __attribute__((aligned(16))) u16 Vt[64 * 136];    // [d][kv] pad 128->136
  __shared__ __attribute__((aligned(16))) u16 Pl[4][16 * 136]; // per-wave P strip
  __shared__ __attribute__((aligned(16))) float maskf[Sn];

  const int tid  = threadIdx.x;
  const int wave = tid >> 6;
  const int lane = tid & 63;
  const int ln   = lane & 15;
  const int quad = lane >> 4;
  const int qt = blockIdx.x & 15;
  const int bh = blockIdx.x >> 4;
  const int b  = bh >> 4;
  const int h  = bh & 15;

  const int mt = flags[1];
  for (int i = tid; i < Sn; i += 256) {
    const int idx = b * Sn + i;
    int nz;
    if (mt == 0)      nz = ((const int*)mask)[idx] != 0;
    else if (mt == 1) nz = ((const signed char*)mask)[idx] != 0;
    else if (mt == 2) nz = ((const u16*)mask)[idx] != 0;
    else              nz = ((const unsigned*)mask)[idx] != 0;
    maskf[i] = nz ? -1e9f : 0.0f;
  }

  // Q fragments (A-operand: m=lane&15, k=quad*8+j); Q pre-scaled by 1/8
  const size_t qoff = (size_t)(b * Sn + qt * 64 + wave * 16 + ln) * Hn + h * DHn;
  bf16x8 qf0 = *(const bf16x8*)&Qb[qoff + quad * 8];
  bf16x8 qf1 = *(const bf16x8*)&Qb[qoff + 32 + quad * 8];

  float mrun[4], lrun[4];
#pragma unroll
  for (int r = 0; r < 4; ++r) { mrun[r] = -INFINITY; lrun[r] = 0.0f; }
  f32x4 acc[4] = {};

  const int kr = tid >> 1, kh = tid & 1;   // K stage: 2 threads/row (64B each)
  const int vd = tid >> 2, vs = tid & 3;   // V stage: 4 threads/row (64B each)
  u16* pw = Pl[wave];

  for (int t8 = 0; t8 < 8; ++t8) {
    const int kv0 = t8 * 128;
    __syncthreads();  // previous Ks/Vt fully consumed
    {
      const u16* g = &Kb[(size_t)(b * Sn + kv0 + kr) * Hn + h * DHn + kh * 32];
      u16* l = &Ks[kr * 72 + kh * 32];
#pragma unroll
      for (int j = 0; j < 4; ++j) *(bf16x8*)(l + j * 8) = *(const bf16x8*)(g + j * 8);
    }
    {
      const u16* g = &Vbt[(size_t)(b * Sn + h * DHn + vd) * Sn + kv0 + vs * 32];
      u16* l = &Vt[vd * 136 + vs * 32];
#pragma unroll
      for (int j = 0; j < 4; ++j) *(bf16x8*)(l + j * 8) = *(const bf16x8*)(g + j * 8);
    }
    __syncthreads();

    // S = Q K^T from LDS (B-operand: n=lane&15 -> kv row, k=quad*8+j -> d)
    f32x4 sc[8];
#pragma unroll
    for (int t = 0; t < 8; ++t) {
      const int row = (t * 16 + ln) * 72;
      bf16x8 kf0 = *(const bf16x8*)&Ks[row + quad * 8];
      bf16x8 kf1 = *(const bf16x8*)&Ks[row + 32 + quad * 8];
      f32x4 z = {};
      z = __builtin_amdgcn_mfma_f32_16x16x32_bf16(qf0, kf0, z, 0, 0, 0);
      z = __builtin_amdgcn_mfma_f32_16x16x32_bf16(qf1, kf1, z, 0, 0, 0);
      sc[t] = z;
    }
    float mf[8];
#pragma unroll
    for (int t = 0; t < 8; ++t) mf[t] = maskf[kv0 + t * 16 + ln];
#pragma unroll
    for (int t = 0; t < 8; ++t)
#pragma unroll
      for (int r = 0; r < 4; ++r) sc[t][r] += mf[t];

    // online softmax per Q-row (row r lives in this quad's 16 lanes)
    float al[4], mx[4];
#pragma unroll
    for (int r = 0; r < 4; ++r) {
      float v = sc[0][r];
#pragma unroll
      for (int t = 1; t < 8; ++t) v = fmaxf(v, sc[t][r]);
      v = fmaxf(v, __shfl_xor(v, 1));
      v = fmaxf(v, __shfl_xor(v, 2));
      v = fmaxf(v, __shfl_xor(v, 4));
      v = fmaxf(v, __shfl_xor(v, 8));
      const float mnew = fmaxf(mrun[r], v);
      al[r] = __expf(mrun[r] - mnew);
      mrun[r] = mnew;
      mx[r] = mnew;
    }
#pragma unroll
    for (int r = 0; r < 4; ++r) {
      float s = 0.0f;
#pragma unroll
      for (int t = 0; t < 8; ++t) {
        const float p = __expf(sc[t][r] - mx[r]);
        sc[t][r] = p;
        s += p;
      }
      s += __shfl_xor(s, 1);
      s += __shfl_xor(s, 2);
      s += __shfl_xor(s, 4);
      s += __shfl_xor(s, 8);
      lrun[r] = lrun[r] * al[r] + s;
    }
    // P: C-layout -> per-wave LDS -> A-layout
#pragma unroll
    for (int t = 0; t < 8; ++t)
#pragma unroll
      for (int r = 0; r < 4; ++r)
        pw[(quad * 4 + r) * 136 + t * 16 + ln] = f2bf(sc[t][r]);
    __syncthreads();  // order scalar P writes vs b128 P reads (and cheap)
#pragma unroll
    for (int dt = 0; dt < 4; ++dt)
#pragma unroll
      for (int r = 0; r < 4; ++r) acc[dt][r] *= al[r];
    bf16x8 pa[4];
#pragma unroll
    for (int c = 0; c < 4; ++c)
      pa[c] = *(const bf16x8*)&pw[ln * 136 + c * 32 + quad * 8];
#pragma unroll
    for (int dt = 0; dt < 4; ++dt) {
      const int vrow = (dt * 16 + ln) * 136;
#pragma unroll
      for (int c = 0; c < 4; ++c) {
        bf16x8 vb = *(const bf16x8*)&Vt[vrow + c * 32 + quad * 8];
        acc[dt] = __builtin_amdgcn_mfma_f32_16x16x32_bf16(pa[c], vb, acc[dt], 0, 0, 0);
      }
    }
  }

#pragma unroll
  for (int dt = 0; dt < 4; ++dt)
#pragma unroll
    for (int r = 0; r < 4; ++r) {
      const int s = qt * 64 + wave * 16 + quad * 4 + r;
      Ctx[(size_t)(b * Sn + s) * Hn + h * DHn + dt * 16 + ln] = f2bf(acc[dt][r] / lrun[r]);
    }
}

extern "C" void kernel_launch(void* const* d_in, const int* in_sizes, int n_in,
                              void* d_out, int out_size, void* d_ws, size_t ws_size,
                              hipStream_t stream) {
  const float* v    = (const float*)d_in[0];
  const float* k    = (const float*)d_in[1];
  const float* q    = (const float*)d_in[2];
  const void*  mask = d_in[3];
  const float* Wq   = (const float*)d_in[4];
  const float* bq   = (const float*)d_in[5];
  const float* Wk   = (const float*)d_in[6];
  const float* bk   = (const float*)d_in[7];
  const float* Wv   = (const float*)d_in[8];
  const float* bv   = (const float*)d_in[9];
  const float* Wm   = (const float*)d_in[10];
  const float* bm   = (const float*)d_in[11];

  // ws layout (56MB + 8B, extents proven safe in round 2/3):
  char* ws = (char*)d_ws;
  u16* qc  = (u16*)(ws);                  // 16MB, consumed by Q-proj -> reused as Vbt
  u16* kc  = (u16*)(ws + (16u << 20));    // 16MB, consumed by K-proj -> reused as Cx
  u16* vc  = (u16*)(ws + (32u << 20));    // 16MB
  u16* Wqc = (u16*)(ws + (48u << 20));    // 2MB each
  u16* Wkc = Wqc + (1u << 20);
  u16* Wvc = Wkc + (1u << 20);
  u16* Wmc = Wvc + (1u << 20);
  int* flags = (int*)(ws + (56u << 20));
  u16* Vbt = qc;
  u16* Cx  = kc;
  u16* Qb  = (u16*)d_out;                 // d_out (32MB f32) hosts Qb+Kb bf16
  u16* Kb  = Qb + (size_t)Mn * Hn;

  sniff_k<<<1, 256, 0, stream>>>(mask, flags);
  convert3<<<3 * 4096, 256, 0, stream>>>(q, k, v, qc, kc, vc);
  convertW<<<4 * 512, 256, 0, stream>>>(Wq, Wk, Wv, Wm, Wqc, Wkc, Wvc, Wmc);

  dim3 grid(Mn / 128, Hn / 128), blk(256);
  gemm_bt<0><<<grid, blk, 0, stream>>>(qc, Wqc, bq, Qb, 0.125f);
  gemm_bt<0><<<grid, blk, 0, stream>>>(kc, Wkc, bk, Kb, 1.0f);
  gemm_bt<2><<<grid, blk, 0, stream>>>(vc, Wvc, bv, Vbt, 1.0f);   // over qc
  attn<<<dim3(Bn * NHn * (Sn / 64)), blk, 0, stream>>>(Qb, Kb, Vbt, mask, flags, Cx); // over kc
  gemm_bt<1><<<grid, blk, 0, stream>>>(Cx, Wmc, bm, d_out, 1.0f);
}